// Round 1
// baseline (282.929 us; speedup 1.0000x reference)
//
#include <hip/hip_runtime.h>
#include <hip/hip_cooperative_groups.h>

namespace cg = cooperative_groups;

// x = (B,1,1024,1024) fp32. Pre-CLAHE chain collapses exactly to
// (x - min)/(max - min). 2 dispatches:
//  k_histlut (COOPERATIVE, grid=T=1024 = 4 blocks/CU exactly):
//      tile -> REGISTERS (fully unrolled; partial unroll dynamic-indexes v[]
//      and spills, the old round-3/5 regression) -> tile min/max ->
//      partials -> grid.sync() -> every block reduces partials (8 KB, L2)
//      -> EXACT 256-bin global-range hist from the register-resident tile
//      (no fine hist, no re-bin approx) -> clip -> wave64 shuffle scan
//      (2 barriers, not 16) -> LUT; block0 writes gmm + y tail.
//  k_apply:  unchanged from the 131 µs version: 8-row strips; interleaved
//      (l0,l1) float2 LUT in LDS (b64 gathers); bins recomputed from x
//      (L3-hot); float4 out.
// Fallback: if cooperative launch is rejected (it needs all 1024 blocks
// co-resident), the proven 3-kernel path (fine-hist 2048) runs instead.
// ws: partials float2[T] @0 ; gmm float2 @8192 ; lut f32[T][256] @16384 ;
//     fineh u16[T][2048] @2MB (fallback only)

#define BINS 256
#define FBINS 2048
#define MAXV 2560u        // int(40 * 16384 / 256)

__global__ __launch_bounds__(256, 4) void k_histlut(const float* __restrict__ x,
                                                    float2* __restrict__ partials,
                                                    float* __restrict__ lut,
                                                    float2* __restrict__ gmm,
                                                    const int* __restrict__ y,
                                                    float* __restrict__ out,
                                                    int N, int tail, int nparts){
  __shared__ unsigned ch[BINS];
  __shared__ float smin[4], smax[4];
  __shared__ float sp[2];
  __shared__ unsigned wsum[4];
  int t = threadIdx.x;
  int tile = blockIdx.x;
  int bc = tile >> 6, ti = (tile >> 3) & 7, tj = tile & 7;
  const float4* x4 = (const float4*)(x + ((size_t)bc * 1024 + ti * 128) * 1024 + tj * 128);
  float4 v[16];
  #pragma unroll
  for (int k = 0; k < 16; k++){
    int p = t + (k << 8);              // 32 float4 per 128-px row
    v[k] = x4[(p >> 5) * 256 + (p & 31)];
  }
  ch[t] = 0u;
  float lmin = INFINITY, lmax = -INFINITY;
  #pragma unroll
  for (int k = 0; k < 16; k++){
    lmin = fminf(lmin, fminf(fminf(v[k].x, v[k].y), fminf(v[k].z, v[k].w)));
    lmax = fmaxf(lmax, fmaxf(fmaxf(v[k].x, v[k].y), fmaxf(v[k].z, v[k].w)));
  }
  for (int o = 32; o > 0; o >>= 1){
    lmin = fminf(lmin, __shfl_down(lmin, o, 64));
    lmax = fmaxf(lmax, __shfl_down(lmax, o, 64));
  }
  int lane = t & 63, wv = t >> 6;
  if (lane == 0){ smin[wv] = lmin; smax[wv] = lmax; }
  __syncthreads();
  if (t == 0){
    float m = smin[0], M = smax[0];
    #pragma unroll
    for (int i = 1; i < 4; i++){ m = fminf(m, smin[i]); M = fmaxf(M, smax[i]); }
    partials[tile] = make_float2(m, M);
    __threadfence();                    // belt: publish before grid sync
  }
  cg::this_grid().sync();               // v[16] stays live in VGPRs across this
  // every block redundantly reduces the 1024 partials (8 KB, L2-broadcast)
  float gmn = INFINITY, gmx = -INFINITY;
  for (int i = t; i < nparts; i += 256){
    float2 p = partials[i];
    gmn = fminf(gmn, p.x);
    gmx = fmaxf(gmx, p.y);
  }
  for (int o = 32; o > 0; o >>= 1){
    gmn = fminf(gmn, __shfl_down(gmn, o, 64));
    gmx = fmaxf(gmx, __shfl_down(gmx, o, 64));
  }
  if (lane == 0){ smin[wv] = gmn; smax[wv] = gmx; }
  __syncthreads();
  if (t == 0){
    float m = smin[0], M = smax[0];
    #pragma unroll
    for (int i = 1; i < 4; i++){ m = fminf(m, smin[i]); M = fmaxf(M, smax[i]); }
    sp[0] = m;
    sp[1] = 1.0f / (M - m);
  }
  __syncthreads();
  float mn = sp[0], inv = sp[1];
  // EXACT hist: same bin expression as k_apply, straight into 256 bins
  #pragma unroll          // FULL unroll: constant v[k] indices, no scratch
  for (int k = 0; k < 16; k++){
    int b0 = min(max((int)(((v[k].x - mn) * inv) * 256.0f), 0), 255);
    int b1 = min(max((int)(((v[k].y - mn) * inv) * 256.0f), 0), 255);
    int b2 = min(max((int)(((v[k].z - mn) * inv) * 256.0f), 0), 255);
    int b3 = min(max((int)(((v[k].w - mn) * inv) * 256.0f), 0), 255);
    atomicAdd(&ch[b0], 1u);
    atomicAdd(&ch[b1], 1u);
    atomicAdd(&ch[b2], 1u);
    atomicAdd(&ch[b3], 1u);
  }
  __syncthreads();
  unsigned h = ch[t];
  if (h > MAXV) h = MAXV;
  // inclusive wave64 shuffle scan + cross-wave offsets (2 barriers total)
  unsigned s = h;
  #pragma unroll
  for (int o = 1; o < 64; o <<= 1){
    unsigned nb = __shfl_up(s, o, 64);
    if (lane >= o) s += nb;
  }
  if (lane == 63) wsum[wv] = s;
  __syncthreads();
  unsigned off = 0;
  #pragma unroll
  for (int i = 0; i < 3; i++) if (i < wv) off += wsum[i];
  unsigned total = wsum[0] + wsum[1] + wsum[2] + wsum[3];
  float residual = (16384.0f - (float)total) * (1.0f / 256.0f);
  float cum = ((float)(s + off) + (float)(t + 1) * residual) * (255.0f / 16384.0f);
  lut[(size_t)tile * BINS + t] = floorf(fminf(fmaxf(cum, 0.0f), 255.0f));
  if (tile == 0){
    if (t == 0) *gmm = make_float2(mn, inv);
    if (t < tail) out[N + t] = (float)y[t];
  }
}

// ---------------- fallback path (proven 3-kernel structure) ----------------

__global__ __launch_bounds__(256, 4) void k_tilestat(const float* __restrict__ x,
                                                     float2* __restrict__ partials,
                                                     unsigned* __restrict__ finehg){
  __shared__ unsigned fh[FBINS];
  __shared__ float smin[4], smax[4];
  __shared__ float sp[2];
  int t = threadIdx.x;
  int tile = blockIdx.x;
  int bc = tile >> 6, ti = (tile >> 3) & 7, tj = tile & 7;
  const float4* x4 = (const float4*)(x + ((size_t)bc * 1024 + ti * 128) * 1024 + tj * 128);
  float4 v[16];
  #pragma unroll
  for (int k = 0; k < 16; k++){
    int p = t + (k << 8);
    v[k] = x4[(p >> 5) * 256 + (p & 31)];
  }
  #pragma unroll
  for (int i = 0; i < FBINS / 256; i++) fh[t + i * 256] = 0u;
  float lmin = INFINITY, lmax = -INFINITY;
  #pragma unroll
  for (int k = 0; k < 16; k++){
    lmin = fminf(lmin, fminf(fminf(v[k].x, v[k].y), fminf(v[k].z, v[k].w)));
    lmax = fmaxf(lmax, fmaxf(fmaxf(v[k].x, v[k].y), fmaxf(v[k].z, v[k].w)));
  }
  for (int o = 32; o > 0; o >>= 1){
    lmin = fminf(lmin, __shfl_down(lmin, o, 64));
    lmax = fmaxf(lmax, __shfl_down(lmax, o, 64));
  }
  int lane = t & 63, wv = t >> 6;
  if (lane == 0){ smin[wv] = lmin; smax[wv] = lmax; }
  __syncthreads();
  if (t == 0){
    float m = smin[0], M = smax[0];
    #pragma unroll
    for (int i = 1; i < 4; i++){ m = fminf(m, smin[i]); M = fmaxf(M, smax[i]); }
    partials[tile] = make_float2(m, M);
    sp[0] = m;
    sp[1] = (float)FBINS / fmaxf(M - m, 1e-30f);
  }
  __syncthreads();
  float tmn = sp[0], tinv = sp[1];
  #pragma unroll
  for (int k = 0; k < 16; k++){
    int b0 = min((int)((v[k].x - tmn) * tinv), FBINS - 1);
    int b1 = min((int)((v[k].y - tmn) * tinv), FBINS - 1);
    int b2 = min((int)((v[k].z - tmn) * tinv), FBINS - 1);
    int b3 = min((int)((v[k].w - tmn) * tinv), FBINS - 1);
    atomicAdd(&fh[b0], 1u);
    atomicAdd(&fh[b1], 1u);
    atomicAdd(&fh[b2], 1u);
    atomicAdd(&fh[b3], 1u);
  }
  __syncthreads();
  unsigned* outp = finehg + (size_t)tile * (FBINS / 2);
  #pragma unroll
  for (int i = 0; i < FBINS / 512; i++){
    int w = t + i * 256;
    outp[w] = (fh[2 * w] & 0xFFFFu) | (fh[2 * w + 1] << 16);
  }
}

__global__ __launch_bounds__(256) void k_lut(const float2* __restrict__ partials,
                                             int nparts,
                                             const unsigned* __restrict__ finehg,
                                             float* __restrict__ lut,
                                             float2* __restrict__ gmm,
                                             const int* __restrict__ y,
                                             float* __restrict__ out,
                                             int N, int tail){
  __shared__ unsigned ch[BINS];
  __shared__ unsigned sc[BINS];
  __shared__ unsigned wsum[4];
  __shared__ float smin[4], smax[4];
  __shared__ float sp[2];
  int t = threadIdx.x;
  int tile = blockIdx.x;
  ch[t] = 0u;
  float lmin = INFINITY, lmax = -INFINITY;
  for (int i = t; i < nparts; i += 256){
    float2 p = partials[i];
    lmin = fminf(lmin, p.x);
    lmax = fmaxf(lmax, p.y);
  }
  for (int o = 32; o > 0; o >>= 1){
    lmin = fminf(lmin, __shfl_down(lmin, o, 64));
    lmax = fmaxf(lmax, __shfl_down(lmax, o, 64));
  }
  int lane = t & 63, wv = t >> 6;
  if (lane == 0){ smin[wv] = lmin; smax[wv] = lmax; }
  __syncthreads();
  if (t == 0){
    float m = smin[0], M = smax[0];
    #pragma unroll
    for (int i = 1; i < 4; i++){ m = fminf(m, smin[i]); M = fmaxf(M, smax[i]); }
    sp[0] = m;
    sp[1] = 1.0f / (M - m);
  }
  __syncthreads();
  float mn = sp[0], inv = sp[1];
  float2 tp = partials[tile];
  float tw = (tp.y - tp.x) * (1.0f / (float)FBINS);
  const unsigned* fhp = finehg + (size_t)tile * (FBINS / 2);
  #pragma unroll
  for (int i = 0; i < 4; i++){
    int w = t + i * 256;
    unsigned pk = fhp[w];
    unsigned c0 = pk & 0xFFFFu, c1 = pk >> 16;
    int f0 = 2 * w;
    if (c0){
      float ctr = tp.x + ((float)f0 + 0.5f) * tw;
      int cb = min(max((int)(((ctr - mn) * inv) * 256.0f), 0), 255);
      atomicAdd(&ch[cb], c0);
    }
    if (c1){
      float ctr = tp.x + ((float)f0 + 1.5f) * tw;
      int cb = min(max((int)(((ctr - mn) * inv) * 256.0f), 0), 255);
      atomicAdd(&ch[cb], c1);
    }
  }
  __syncthreads();
  unsigned h = ch[t];
  if (h > MAXV) h = MAXV;
  unsigned s = h;
  for (int o = 32; o > 0; o >>= 1) s += __shfl_down(s, o, 64);
  if (lane == 0) wsum[wv] = s;
  __syncthreads();
  unsigned total = wsum[0] + wsum[1] + wsum[2] + wsum[3];
  float residual = (16384.0f - (float)total) * (1.0f / 256.0f);
  sc[t] = h;
  __syncthreads();
  for (int o = 1; o < 256; o <<= 1){
    unsigned pv = (t >= o) ? sc[t - o] : 0u;
    __syncthreads();
    sc[t] += pv;
    __syncthreads();
  }
  float cum = ((float)sc[t] + (float)(t + 1) * residual) * (255.0f / 16384.0f);
  lut[(size_t)tile * BINS + t] = floorf(fminf(fmaxf(cum, 0.0f), 255.0f));
  if (tile == 0){
    if (t == 0) *gmm = make_float2(mn, inv);
    if (t < tail) out[N + t] = (float)y[t];
  }
}

// one block = 8-row strip (i0/i1 uniform: band boundaries 64+128k are 8-aligned)
__global__ __launch_bounds__(256) void k_apply(const float* __restrict__ x,
                                               const float2* __restrict__ gmm,
                                               const float* __restrict__ lutg,
                                               float* __restrict__ out){
  __shared__ float2 lint[2048];     // (l0,l1) interleaved, 16 KB
  int t = threadIdx.x;
  int strip = blockIdx.x;
  int b = strip >> 7;
  int r0 = (strip & 127) << 3;
  float gi = fminf(fmaxf((r0 + 0.5f) * (1.0f / 128.0f) - 0.5f, 0.0f), 7.0f);
  int i0 = (int)gi;
  int i1 = min(i0 + 1, 7);
  const float* g0 = lutg + ((size_t)b * 8 + i0) * 2048;
  const float* g1 = lutg + ((size_t)b * 8 + i1) * 2048;
  #pragma unroll
  for (int i = 0; i < 8; i++){
    int k = t + i * 256;
    lint[k] = make_float2(g0[k], g1[k]);
  }
  float2 mmv = *gmm;
  float mn = mmv.x, inv = mmv.y;
  int j0[4], j1[4];
  float wx[4];
  #pragma unroll
  for (int c = 0; c < 4; c++){
    int col = (t << 2) + c;
    float gj = fminf(fmaxf((col + 0.5f) * (1.0f / 128.0f) - 0.5f, 0.0f), 7.0f);
    j0[c] = (int)gj;
    j1[c] = min(j0[c] + 1, 7);
    wx[c] = gj - (float)j0[c];
  }
  size_t base4 = ((size_t)b * 1024 + r0) * 256;   // float4 units
  __syncthreads();
  #pragma unroll
  for (int r = 0; r < 8; r++){
    int h = r0 + r;
    float giw = fminf(fmaxf((h + 0.5f) * (1.0f / 128.0f) - 0.5f, 0.0f), 7.0f);
    float wy = giw - (float)i0;
    float4 xv = ((const float4*)x)[base4 + r * 256 + t];
    int bi[4];
    bi[0] = min(max((int)(((xv.x - mn) * inv) * 256.0f), 0), 255);
    bi[1] = min(max((int)(((xv.y - mn) * inv) * 256.0f), 0), 255);
    bi[2] = min(max((int)(((xv.z - mn) * inv) * 256.0f), 0), 255);
    bi[3] = min(max((int)(((xv.w - mn) * inv) * 256.0f), 0), 255);
    float res[4];
    #pragma unroll
    for (int c = 0; c < 4; c++){
      float2 p0 = lint[(j0[c] << 8) + bi[c]];   // (v00, v10)
      float2 p1 = lint[(j1[c] << 8) + bi[c]];   // (v01, v11)
      float top = p0.x + wx[c] * (p1.x - p0.x);
      float bot = p0.y + wx[c] * (p1.y - p0.y);
      res[c] = (top + wy * (bot - top)) * (1.0f / 255.0f);
    }
    ((float4*)out)[base4 + r * 256 + t] = make_float4(res[0], res[1], res[2], res[3]);
  }
}

extern "C" void kernel_launch(void* const* d_in, const int* in_sizes, int n_in,
                              void* d_out, int out_size, void* d_ws, size_t ws_size,
                              hipStream_t stream){
  const float* x = (const float*)d_in[0];
  const int* y = (const int*)d_in[1];
  float* out = (float*)d_out;
  int N = in_sizes[0];
  int B = N >> 20;
  int T = B * 64;
  float2* partials = (float2*)d_ws;
  float2* gmm = (float2*)((char*)d_ws + 8192);
  float* lut = (float*)((char*)d_ws + 16384);
  unsigned* fineh = (unsigned*)((char*)d_ws + (2u << 20));   // fallback only
  int tail = out_size - N;

  void* args[] = { (void*)&x, (void*)&partials, (void*)&lut, (void*)&gmm,
                   (void*)&y, (void*)&out, (void*)&N, (void*)&tail, (void*)&T };
  hipError_t ce = hipLaunchCooperativeKernel((const void*)k_histlut,
                                             dim3((unsigned)T), dim3(256),
                                             args, 0, stream);
  if (ce != hipSuccess){
    // co-residency or capture rejection: proven 3-kernel path
    hipLaunchKernelGGL(k_tilestat, dim3(T), dim3(256), 0, stream, x, partials, fineh);
    hipLaunchKernelGGL(k_lut, dim3(T), dim3(256), 0, stream,
                       partials, T, fineh, lut, gmm, y, out, N, tail);
  }
  hipLaunchKernelGGL(k_apply, dim3(B * 128), dim3(256), 0, stream,
                     x, gmm, lut, out);
}

// Round 2
// 134.409 us; speedup vs baseline: 2.1050x; 2.1050x over previous
//
#include <hip/hip_runtime.h>

// x = (B,1,1024,1024) fp32. Pre-CLAHE chain collapses exactly to
// (x - min)/(max - min). 3 graph-capturable dispatches (NO cooperative
// launch — round-1 showed this_grid().sync() spills the tile regs
// (VGPR 44 < 64 needed) and idles 160 µs at 3% VALUBusy):
//  k_minmax:  pure streaming min/max reduce -> partials[B*128].
//             64 MB HBM read, ~11 µs. After this, x is L3-resident.
//  k_histlut: one block per tile. Every block reduces partials (16 KB,
//             L2-broadcast), re-reads its own 64 KB tile from L3, builds
//             the EXACT 256-bin global-range hist (4 per-wave LDS copies —
//             round-1 measured 1.33M conflict cycles on a single shared
//             256-bin hist), clip -> wave64 shuffle scan (2 barriers,
//             not the old 16-barrier Hillis-Steele) -> LUT.
//             Replaces the old fine-hist(2048) + u16 pack + 4 MB ws
//             round-trip + bin-center re-bin approximation.
//  k_apply:   unchanged from the 131 µs version: 8-row strips;
//             interleaved (l0,l1) float2 LUT in LDS (b64 gathers); exact
//             bins recomputed from x (L3-hot); float4 out.
// ws: partials float2[B*128] @0 ; gmm float2 @16384 ; lut f32[T][256] @20480

#define BINS 256
#define MAXV 2560u        // int(40 * 16384 / 256)

__global__ __launch_bounds__(256, 8) void k_minmax(const float4* __restrict__ x4,
                                                   float2* __restrict__ partials,
                                                   int nf4){
  __shared__ float smin[4], smax[4];
  int t = threadIdx.x;
  int gid = blockIdx.x * 256 + t;
  int stride = gridDim.x * 256;
  float lmin = INFINITY, lmax = -INFINITY;
  for (int i = gid; i < nf4; i += stride){
    float4 v = x4[i];
    lmin = fminf(lmin, fminf(fminf(v.x, v.y), fminf(v.z, v.w)));
    lmax = fmaxf(lmax, fmaxf(fmaxf(v.x, v.y), fmaxf(v.z, v.w)));
  }
  for (int o = 32; o > 0; o >>= 1){
    lmin = fminf(lmin, __shfl_down(lmin, o, 64));
    lmax = fmaxf(lmax, __shfl_down(lmax, o, 64));
  }
  int lane = t & 63, wv = t >> 6;
  if (lane == 0){ smin[wv] = lmin; smax[wv] = lmax; }
  __syncthreads();
  if (t == 0){
    float m = smin[0], M = smax[0];
    #pragma unroll
    for (int i = 1; i < 4; i++){ m = fminf(m, smin[i]); M = fmaxf(M, smax[i]); }
    partials[blockIdx.x] = make_float2(m, M);
  }
}

__global__ __launch_bounds__(256, 4) void k_histlut(const float* __restrict__ x,
                                                    const float2* __restrict__ partials,
                                                    int nparts,
                                                    float* __restrict__ lut,
                                                    float2* __restrict__ gmm,
                                                    const int* __restrict__ y,
                                                    float* __restrict__ out,
                                                    int N, int tail){
  __shared__ unsigned hs[4][BINS];   // per-wave copies: no cross-wave atomic serialization
  __shared__ float smin[4], smax[4];
  __shared__ float sp[2];
  __shared__ unsigned wsum[4];
  int t = threadIdx.x;
  int tile = blockIdx.x;
  int lane = t & 63, wv = t >> 6;
  hs[0][t] = 0u; hs[1][t] = 0u; hs[2][t] = 0u; hs[3][t] = 0u;
  // redundant global min/max reduce (nparts float2 from L2, ~16 KB)
  float gmn = INFINITY, gmx = -INFINITY;
  for (int i = t; i < nparts; i += 256){
    float2 p = partials[i];
    gmn = fminf(gmn, p.x);
    gmx = fmaxf(gmx, p.y);
  }
  for (int o = 32; o > 0; o >>= 1){
    gmn = fminf(gmn, __shfl_down(gmn, o, 64));
    gmx = fmaxf(gmx, __shfl_down(gmx, o, 64));
  }
  if (lane == 0){ smin[wv] = gmn; smax[wv] = gmx; }
  __syncthreads();
  if (t == 0){
    float m = smin[0], M = smax[0];
    #pragma unroll
    for (int i = 1; i < 4; i++){ m = fminf(m, smin[i]); M = fmaxf(M, smax[i]); }
    sp[0] = m;
    sp[1] = 1.0f / (M - m);
  }
  __syncthreads();
  float mn = sp[0], inv = sp[1];
  // exact 256-bin hist of this tile in the global range (same bin expr as k_apply)
  int bc = tile >> 6, ti = (tile >> 3) & 7, tj = tile & 7;
  const float4* x4 = (const float4*)(x + ((size_t)bc * 1024 + ti * 128) * 1024 + tj * 128);
  unsigned* h = hs[wv];
  #pragma unroll
  for (int k = 0; k < 16; k++){
    int p = t + (k << 8);              // 32 float4 per 128-px row
    float4 v = x4[(p >> 5) * 256 + (p & 31)];
    int b0 = min(max((int)(((v.x - mn) * inv) * 256.0f), 0), 255);
    int b1 = min(max((int)(((v.y - mn) * inv) * 256.0f), 0), 255);
    int b2 = min(max((int)(((v.z - mn) * inv) * 256.0f), 0), 255);
    int b3 = min(max((int)(((v.w - mn) * inv) * 256.0f), 0), 255);
    atomicAdd(&h[b0], 1u);
    atomicAdd(&h[b1], 1u);
    atomicAdd(&h[b2], 1u);
    atomicAdd(&h[b3], 1u);
  }
  __syncthreads();
  unsigned hh = hs[0][t] + hs[1][t] + hs[2][t] + hs[3][t];
  if (hh > MAXV) hh = MAXV;
  // inclusive wave64 shuffle scan + cross-wave offsets (2 barriers total)
  unsigned s = hh;
  #pragma unroll
  for (int o = 1; o < 64; o <<= 1){
    unsigned nb = __shfl_up(s, o, 64);
    if (lane >= o) s += nb;
  }
  if (lane == 63) wsum[wv] = s;
  __syncthreads();
  unsigned off = 0;
  #pragma unroll
  for (int i = 0; i < 3; i++) if (i < wv) off += wsum[i];
  unsigned total = wsum[0] + wsum[1] + wsum[2] + wsum[3];
  float residual = (16384.0f - (float)total) * (1.0f / 256.0f);
  float cum = ((float)(s + off) + (float)(t + 1) * residual) * (255.0f / 16384.0f);
  lut[(size_t)tile * BINS + t] = floorf(fminf(fmaxf(cum, 0.0f), 255.0f));
  if (tile == 0){
    if (t == 0) *gmm = make_float2(mn, inv);
    if (t < tail) out[N + t] = (float)y[t];
  }
}

// one block = 8-row strip (i0/i1 uniform: band boundaries 64+128k are 8-aligned)
__global__ __launch_bounds__(256) void k_apply(const float* __restrict__ x,
                                               const float2* __restrict__ gmm,
                                               const float* __restrict__ lutg,
                                               float* __restrict__ out){
  __shared__ float2 lint[2048];     // (l0,l1) interleaved, 16 KB
  int t = threadIdx.x;
  int strip = blockIdx.x;
  int b = strip >> 7;
  int r0 = (strip & 127) << 3;
  float gi = fminf(fmaxf((r0 + 0.5f) * (1.0f / 128.0f) - 0.5f, 0.0f), 7.0f);
  int i0 = (int)gi;
  int i1 = min(i0 + 1, 7);
  const float* g0 = lutg + ((size_t)b * 8 + i0) * 2048;
  const float* g1 = lutg + ((size_t)b * 8 + i1) * 2048;
  #pragma unroll
  for (int i = 0; i < 8; i++){
    int k = t + i * 256;
    lint[k] = make_float2(g0[k], g1[k]);
  }
  float2 mmv = *gmm;
  float mn = mmv.x, inv = mmv.y;
  int j0[4], j1[4];
  float wx[4];
  #pragma unroll
  for (int c = 0; c < 4; c++){
    int col = (t << 2) + c;
    float gj = fminf(fmaxf((col + 0.5f) * (1.0f / 128.0f) - 0.5f, 0.0f), 7.0f);
    j0[c] = (int)gj;
    j1[c] = min(j0[c] + 1, 7);
    wx[c] = gj - (float)j0[c];
  }
  size_t base4 = ((size_t)b * 1024 + r0) * 256;   // float4 units
  __syncthreads();
  #pragma unroll
  for (int r = 0; r < 8; r++){
    int h = r0 + r;
    float giw = fminf(fmaxf((h + 0.5f) * (1.0f / 128.0f) - 0.5f, 0.0f), 7.0f);
    float wy = giw - (float)i0;
    float4 xv = ((const float4*)x)[base4 + r * 256 + t];
    int bi[4];
    bi[0] = min(max((int)(((xv.x - mn) * inv) * 256.0f), 0), 255);
    bi[1] = min(max((int)(((xv.y - mn) * inv) * 256.0f), 0), 255);
    bi[2] = min(max((int)(((xv.z - mn) * inv) * 256.0f), 0), 255);
    bi[3] = min(max((int)(((xv.w - mn) * inv) * 256.0f), 0), 255);
    float res[4];
    #pragma unroll
    for (int c = 0; c < 4; c++){
      float2 p0 = lint[(j0[c] << 8) + bi[c]];   // (v00, v10)
      float2 p1 = lint[(j1[c] << 8) + bi[c]];   // (v01, v11)
      float top = p0.x + wx[c] * (p1.x - p0.x);
      float bot = p0.y + wx[c] * (p1.y - p0.y);
      res[c] = (top + wy * (bot - top)) * (1.0f / 255.0f);
    }
    ((float4*)out)[base4 + r * 256 + t] = make_float4(res[0], res[1], res[2], res[3]);
  }
}

extern "C" void kernel_launch(void* const* d_in, const int* in_sizes, int n_in,
                              void* d_out, int out_size, void* d_ws, size_t ws_size,
                              hipStream_t stream){
  const float* x = (const float*)d_in[0];
  const int* y = (const int*)d_in[1];
  float* out = (float*)d_out;
  int N = in_sizes[0];
  int B = N >> 20;
  int T = B * 64;
  int nmm = B * 128;                 // k_minmax blocks (= k_apply grid)
  float2* partials = (float2*)d_ws;
  float2* gmm = (float2*)((char*)d_ws + 16384);
  float* lut = (float*)((char*)d_ws + 20480);
  int tail = out_size - N;

  hipLaunchKernelGGL(k_minmax, dim3(nmm), dim3(256), 0, stream,
                     (const float4*)x, partials, N >> 2);
  hipLaunchKernelGGL(k_histlut, dim3(T), dim3(256), 0, stream,
                     x, partials, nmm, lut, gmm, y, out, N, tail);
  hipLaunchKernelGGL(k_apply, dim3(B * 128), dim3(256), 0, stream,
                     x, gmm, lut, out);
}

// Round 3
// 130.311 us; speedup vs baseline: 2.1712x; 1.0314x over previous
//
#include <hip/hip_runtime.h>

// x = (B,1,1024,1024) fp32. Pre-CLAHE chain collapses exactly to
// (x - min)/(max - min). 3 graph-captured dispatches (cooperative launch is
// dead: round-1 showed grid.sync() spills the reg-tile and breaks capture).
// x is read exactly twice (HBM in k1, L3-hot in k3) — round-2 proved the
// "exact bin" variant's extra L3 pass costs ~3 µs and buys nothing
// (absmax identical 0.01953 for both: error is LUT quantization).
//  k_tilestat: per-tile block reads tile into REGISTERS (all loops FULLY
//              unrolled — partial unroll dynamic-indexes v[] and spills) ->
//              tile min/max partials -> 2048-bin fine hist over the tile's
//              own range (LDS) -> packed u16 out
//  k_lut:      reduce partials -> global mn/inv; rebin fine(2048)->coarse(256)
//              with thread-owns-8-CONSECUTIVE-fine-bins (uint4 load) +
//              run-accumulation => ~1-2 atomics/thread instead of 8 atomics
//              with 8-way same-address pileup (old interleaved layout);
//              clip -> wave64 shuffle scan (2 barriers, not 16) -> LUT;
//              block0 writes gmm + y tail
//  k_apply:    unchanged from 131 µs version: 8-row strips; interleaved
//              (l0,l1) float2 LUT in LDS (b64 gathers); bins recomputed from
//              x (L3-hot); float4 out
// ws: partials float2[T] @0 ; gmm float2 @8192 ; fineh u16[T][2048] @16384 ;
//     lut f32[T][256] after. (T = B*64 tiles)

#define BINS 256
#define FBINS 2048
#define MAXV 2560u        // int(40 * 16384 / 256)

__global__ __launch_bounds__(256, 4) void k_tilestat(const float* __restrict__ x,
                                                     float2* __restrict__ partials,
                                                     unsigned* __restrict__ finehg){
  __shared__ unsigned fh[FBINS];
  __shared__ float smin[4], smax[4];
  __shared__ float sp[2];
  int t = threadIdx.x;
  int tile = blockIdx.x;
  int bc = tile >> 6, ti = (tile >> 3) & 7, tj = tile & 7;
  const float4* x4 = (const float4*)(x + ((size_t)bc * 1024 + ti * 128) * 1024 + tj * 128);
  float4 v[16];
  #pragma unroll
  for (int k = 0; k < 16; k++){
    int p = t + (k << 8);              // 32 float4 per 128-px row
    v[k] = x4[(p >> 5) * 256 + (p & 31)];
  }
  #pragma unroll
  for (int i = 0; i < FBINS / 256; i++) fh[t + i * 256] = 0u;
  float lmin = INFINITY, lmax = -INFINITY;
  #pragma unroll
  for (int k = 0; k < 16; k++){
    lmin = fminf(lmin, fminf(fminf(v[k].x, v[k].y), fminf(v[k].z, v[k].w)));
    lmax = fmaxf(lmax, fmaxf(fmaxf(v[k].x, v[k].y), fmaxf(v[k].z, v[k].w)));
  }
  for (int o = 32; o > 0; o >>= 1){
    lmin = fminf(lmin, __shfl_down(lmin, o, 64));
    lmax = fmaxf(lmax, __shfl_down(lmax, o, 64));
  }
  int lane = t & 63, wv = t >> 6;
  if (lane == 0){ smin[wv] = lmin; smax[wv] = lmax; }
  __syncthreads();
  if (t == 0){
    float m = smin[0], M = smax[0];
    #pragma unroll
    for (int i = 1; i < 4; i++){ m = fminf(m, smin[i]); M = fmaxf(M, smax[i]); }
    partials[tile] = make_float2(m, M);
    sp[0] = m;
    sp[1] = (float)FBINS / fmaxf(M - m, 1e-30f);
  }
  __syncthreads();
  float tmn = sp[0], tinv = sp[1];
  #pragma unroll          // FULL unroll: constant v[k] indices, no scratch
  for (int k = 0; k < 16; k++){
    int b0 = min((int)((v[k].x - tmn) * tinv), FBINS - 1);
    int b1 = min((int)((v[k].y - tmn) * tinv), FBINS - 1);
    int b2 = min((int)((v[k].z - tmn) * tinv), FBINS - 1);
    int b3 = min((int)((v[k].w - tmn) * tinv), FBINS - 1);
    atomicAdd(&fh[b0], 1u);
    atomicAdd(&fh[b1], 1u);
    atomicAdd(&fh[b2], 1u);
    atomicAdd(&fh[b3], 1u);
  }
  __syncthreads();
  unsigned* outp = finehg + (size_t)tile * (FBINS / 2);
  #pragma unroll
  for (int i = 0; i < FBINS / 512; i++){     // 1024 packed words, 4/thread
    int w = t + i * 256;
    outp[w] = (fh[2 * w] & 0xFFFFu) | (fh[2 * w + 1] << 16);
  }
}

__global__ __launch_bounds__(256) void k_lut(const float2* __restrict__ partials,
                                             int nparts,
                                             const unsigned* __restrict__ finehg,
                                             float* __restrict__ lut,
                                             float2* __restrict__ gmm,
                                             const int* __restrict__ y,
                                             float* __restrict__ out,
                                             int N, int tail){
  __shared__ unsigned ch[BINS];
  __shared__ unsigned wsum[4];
  __shared__ float smin[4], smax[4];
  __shared__ float sp[2];
  int t = threadIdx.x;
  int tile = blockIdx.x;
  int lane = t & 63, wv = t >> 6;
  ch[t] = 0u;
  // global min/max reduce: nparts float2 (8 KB, L2-broadcast)
  float lmin = INFINITY, lmax = -INFINITY;
  for (int i = t; i < nparts; i += 256){
    float2 p = partials[i];
    lmin = fminf(lmin, p.x);
    lmax = fmaxf(lmax, p.y);
  }
  for (int o = 32; o > 0; o >>= 1){
    lmin = fminf(lmin, __shfl_down(lmin, o, 64));
    lmax = fmaxf(lmax, __shfl_down(lmax, o, 64));
  }
  if (lane == 0){ smin[wv] = lmin; smax[wv] = lmax; }
  __syncthreads();
  if (t == 0){
    float m = smin[0], M = smax[0];
    #pragma unroll
    for (int i = 1; i < 4; i++){ m = fminf(m, smin[i]); M = fmaxf(M, smax[i]); }
    sp[0] = m;
    sp[1] = 1.0f / (M - m);
  }
  __syncthreads();
  float mn = sp[0], inv = sp[1];
  float2 tp = partials[tile];
  float tw = (tp.y - tp.x) * (1.0f / (float)FBINS);
  // thread t owns fine bins [8t, 8t+8): one coalesced uint4 (16 B/lane),
  // monotone fine->coarse map => run-accumulate, ~1-2 atomics/thread
  const uint4* fhp4 = (const uint4*)(finehg + (size_t)tile * (FBINS / 2));
  uint4 pk = fhp4[t];
  unsigned c[8];
  c[0] = pk.x & 0xFFFFu; c[1] = pk.x >> 16;
  c[2] = pk.y & 0xFFFFu; c[3] = pk.y >> 16;
  c[4] = pk.z & 0xFFFFu; c[5] = pk.z >> 16;
  c[6] = pk.w & 0xFFFFu; c[7] = pk.w >> 16;
  int f0 = t << 3;
  unsigned acc = 0;
  int cur = -1;
  #pragma unroll
  for (int i = 0; i < 8; i++){
    if (!c[i]) continue;               // skip-zero keeps run merging valid
    float ctr = tp.x + ((float)(f0 + i) + 0.5f) * tw;
    int cb = min(max((int)(((ctr - mn) * inv) * 256.0f), 0), 255);
    if (cb != cur){
      if (acc) atomicAdd(&ch[cur], acc);
      acc = 0u;
      cur = cb;
    }
    acc += c[i];
  }
  if (acc) atomicAdd(&ch[cur], acc);
  __syncthreads();
  unsigned h = ch[t];
  if (h > MAXV) h = MAXV;
  // inclusive wave64 shuffle scan + cross-wave offsets (2 barriers total)
  unsigned s = h;
  #pragma unroll
  for (int o = 1; o < 64; o <<= 1){
    unsigned nb = __shfl_up(s, o, 64);
    if (lane >= o) s += nb;
  }
  if (lane == 63) wsum[wv] = s;
  __syncthreads();
  unsigned off = 0;
  #pragma unroll
  for (int i = 0; i < 3; i++) if (i < wv) off += wsum[i];
  unsigned total = wsum[0] + wsum[1] + wsum[2] + wsum[3];
  float residual = (16384.0f - (float)total) * (1.0f / 256.0f);
  float cum = ((float)(s + off) + (float)(t + 1) * residual) * (255.0f / 16384.0f);
  lut[(size_t)tile * BINS + t] = floorf(fminf(fmaxf(cum, 0.0f), 255.0f));
  if (tile == 0){
    if (t == 0) *gmm = make_float2(mn, inv);
    if (t < tail) out[N + t] = (float)y[t];
  }
}

// one block = 8-row strip (i0/i1 uniform: band boundaries 64+128k are 8-aligned)
__global__ __launch_bounds__(256) void k_apply(const float* __restrict__ x,
                                               const float2* __restrict__ gmm,
                                               const float* __restrict__ lutg,
                                               float* __restrict__ out){
  __shared__ float2 lint[2048];     // (l0,l1) interleaved, 16 KB
  int t = threadIdx.x;
  int strip = blockIdx.x;
  int b = strip >> 7;
  int r0 = (strip & 127) << 3;
  float gi = fminf(fmaxf((r0 + 0.5f) * (1.0f / 128.0f) - 0.5f, 0.0f), 7.0f);
  int i0 = (int)gi;
  int i1 = min(i0 + 1, 7);
  const float* g0 = lutg + ((size_t)b * 8 + i0) * 2048;
  const float* g1 = lutg + ((size_t)b * 8 + i1) * 2048;
  #pragma unroll
  for (int i = 0; i < 8; i++){
    int k = t + i * 256;
    lint[k] = make_float2(g0[k], g1[k]);
  }
  float2 mmv = *gmm;
  float mn = mmv.x, inv = mmv.y;
  int j0[4], j1[4];
  float wx[4];
  #pragma unroll
  for (int c = 0; c < 4; c++){
    int col = (t << 2) + c;
    float gj = fminf(fmaxf((col + 0.5f) * (1.0f / 128.0f) - 0.5f, 0.0f), 7.0f);
    j0[c] = (int)gj;
    j1[c] = min(j0[c] + 1, 7);
    wx[c] = gj - (float)j0[c];
  }
  size_t base4 = ((size_t)b * 1024 + r0) * 256;   // float4 units
  __syncthreads();
  #pragma unroll
  for (int r = 0; r < 8; r++){
    int h = r0 + r;
    float giw = fminf(fmaxf((h + 0.5f) * (1.0f / 128.0f) - 0.5f, 0.0f), 7.0f);
    float wy = giw - (float)i0;
    float4 xv = ((const float4*)x)[base4 + r * 256 + t];
    int bi[4];
    bi[0] = min(max((int)(((xv.x - mn) * inv) * 256.0f), 0), 255);
    bi[1] = min(max((int)(((xv.y - mn) * inv) * 256.0f), 0), 255);
    bi[2] = min(max((int)(((xv.z - mn) * inv) * 256.0f), 0), 255);
    bi[3] = min(max((int)(((xv.w - mn) * inv) * 256.0f), 0), 255);
    float res[4];
    #pragma unroll
    for (int c = 0; c < 4; c++){
      float2 p0 = lint[(j0[c] << 8) + bi[c]];   // (v00, v10)
      float2 p1 = lint[(j1[c] << 8) + bi[c]];   // (v01, v11)
      float top = p0.x + wx[c] * (p1.x - p0.x);
      float bot = p0.y + wx[c] * (p1.y - p0.y);
      res[c] = (top + wy * (bot - top)) * (1.0f / 255.0f);
    }
    ((float4*)out)[base4 + r * 256 + t] = make_float4(res[0], res[1], res[2], res[3]);
  }
}

extern "C" void kernel_launch(void* const* d_in, const int* in_sizes, int n_in,
                              void* d_out, int out_size, void* d_ws, size_t ws_size,
                              hipStream_t stream){
  const float* x = (const float*)d_in[0];
  const int* y = (const int*)d_in[1];
  float* out = (float*)d_out;
  int N = in_sizes[0];
  int B = N >> 20;
  int T = B * 64;
  float2* partials = (float2*)d_ws;
  float2* gmm = (float2*)((char*)d_ws + 8192);
  unsigned* fineh = (unsigned*)((char*)d_ws + 16384);
  float* lut = (float*)((char*)d_ws + 16384 + (size_t)T * (FBINS * 2));
  int tail = out_size - N;

  hipLaunchKernelGGL(k_tilestat, dim3(T), dim3(256), 0, stream, x, partials, fineh);
  hipLaunchKernelGGL(k_lut, dim3(T), dim3(256), 0, stream,
                     partials, T, fineh, lut, gmm, y, out, N, tail);
  hipLaunchKernelGGL(k_apply, dim3(B * 128), dim3(256), 0, stream,
                     x, gmm, lut, out);
}

// Round 4
// 130.283 us; speedup vs baseline: 2.1717x; 1.0002x over previous
//
#include <hip/hip_runtime.h>

// x = (B,1,1024,1024) fp32. Pre-CLAHE chain collapses exactly to
// (x - min)/(max - min). 3 graph-captured dispatches. x read exactly twice
// (HBM in k1, L3-hot in k3). ~83 µs of the timed window is harness poison
// fills (2 x 256 MB fillBufferAligned) — untouchable.
//  k_tilestat: per-tile block reads tile into REGISTERS (all loops FULLY
//              unrolled — partial unroll dynamic-indexes v[] and spills) ->
//              tile min/max partials -> 2048-bin fine hist over the tile's
//              own range (LDS) -> packed u16 out   [unchanged, proven]
//  k_lut:      reduce partials -> global mn/inv; rebin fine->coarse with
//              thread-owns-8-consecutive-fine-bins + run-accumulation
//              (~1-2 atomics/thread); clip -> wave64 shuffle scan (2
//              barriers) -> LUT as U8 (values are exact ints 0..255 —
//              floorf output, u8 is lossless)
//  k_apply:    8-row strips. NEW: packed-u32 LDS LUT
//              pkl[(j<<8)+b] = l_i0(j)|l_i1(j)<<8|l_i0(j+1)<<16|l_i1(j+1)<<24
//              (8 KB, j+1 clamp folded at build). Per pixel ONE ds_read_b32
//              (bank = b%32, full spread => ~conflict-free; was 2x b64 on a
//              float2 table with only 16 distinct bank-pairs => ~4-way
//              conflicts, 64 LDS ops/thread). Unpack via cvt_f32_ubyte.
// ws: partials float2[T] @0 ; gmm float2 @8192 ; fineh u16[T][2048] @16384 ;
//     lut u8[T][256] after. (T = B*64 tiles)

#define BINS 256
#define FBINS 2048
#define MAXV 2560u        // int(40 * 16384 / 256)

__global__ __launch_bounds__(256, 4) void k_tilestat(const float* __restrict__ x,
                                                     float2* __restrict__ partials,
                                                     unsigned* __restrict__ finehg){
  __shared__ unsigned fh[FBINS];
  __shared__ float smin[4], smax[4];
  __shared__ float sp[2];
  int t = threadIdx.x;
  int tile = blockIdx.x;
  int bc = tile >> 6, ti = (tile >> 3) & 7, tj = tile & 7;
  const float4* x4 = (const float4*)(x + ((size_t)bc * 1024 + ti * 128) * 1024 + tj * 128);
  float4 v[16];
  #pragma unroll
  for (int k = 0; k < 16; k++){
    int p = t + (k << 8);              // 32 float4 per 128-px row
    v[k] = x4[(p >> 5) * 256 + (p & 31)];
  }
  #pragma unroll
  for (int i = 0; i < FBINS / 256; i++) fh[t + i * 256] = 0u;
  float lmin = INFINITY, lmax = -INFINITY;
  #pragma unroll
  for (int k = 0; k < 16; k++){
    lmin = fminf(lmin, fminf(fminf(v[k].x, v[k].y), fminf(v[k].z, v[k].w)));
    lmax = fmaxf(lmax, fmaxf(fmaxf(v[k].x, v[k].y), fmaxf(v[k].z, v[k].w)));
  }
  for (int o = 32; o > 0; o >>= 1){
    lmin = fminf(lmin, __shfl_down(lmin, o, 64));
    lmax = fmaxf(lmax, __shfl_down(lmax, o, 64));
  }
  int lane = t & 63, wv = t >> 6;
  if (lane == 0){ smin[wv] = lmin; smax[wv] = lmax; }
  __syncthreads();
  if (t == 0){
    float m = smin[0], M = smax[0];
    #pragma unroll
    for (int i = 1; i < 4; i++){ m = fminf(m, smin[i]); M = fmaxf(M, smax[i]); }
    partials[tile] = make_float2(m, M);
    sp[0] = m;
    sp[1] = (float)FBINS / fmaxf(M - m, 1e-30f);
  }
  __syncthreads();
  float tmn = sp[0], tinv = sp[1];
  #pragma unroll          // FULL unroll: constant v[k] indices, no scratch
  for (int k = 0; k < 16; k++){
    int b0 = min((int)((v[k].x - tmn) * tinv), FBINS - 1);
    int b1 = min((int)((v[k].y - tmn) * tinv), FBINS - 1);
    int b2 = min((int)((v[k].z - tmn) * tinv), FBINS - 1);
    int b3 = min((int)((v[k].w - tmn) * tinv), FBINS - 1);
    atomicAdd(&fh[b0], 1u);
    atomicAdd(&fh[b1], 1u);
    atomicAdd(&fh[b2], 1u);
    atomicAdd(&fh[b3], 1u);
  }
  __syncthreads();
  unsigned* outp = finehg + (size_t)tile * (FBINS / 2);
  #pragma unroll
  for (int i = 0; i < FBINS / 512; i++){     // 1024 packed words, 4/thread
    int w = t + i * 256;
    outp[w] = (fh[2 * w] & 0xFFFFu) | (fh[2 * w + 1] << 16);
  }
}

__global__ __launch_bounds__(256) void k_lut(const float2* __restrict__ partials,
                                             int nparts,
                                             const unsigned* __restrict__ finehg,
                                             unsigned char* __restrict__ lut,
                                             float2* __restrict__ gmm,
                                             const int* __restrict__ y,
                                             float* __restrict__ out,
                                             int N, int tail){
  __shared__ unsigned ch[BINS];
  __shared__ unsigned wsum[4];
  __shared__ float smin[4], smax[4];
  __shared__ float sp[2];
  int t = threadIdx.x;
  int tile = blockIdx.x;
  int lane = t & 63, wv = t >> 6;
  ch[t] = 0u;
  // global min/max reduce: nparts float2 (8 KB, L2-broadcast)
  float lmin = INFINITY, lmax = -INFINITY;
  for (int i = t; i < nparts; i += 256){
    float2 p = partials[i];
    lmin = fminf(lmin, p.x);
    lmax = fmaxf(lmax, p.y);
  }
  for (int o = 32; o > 0; o >>= 1){
    lmin = fminf(lmin, __shfl_down(lmin, o, 64));
    lmax = fmaxf(lmax, __shfl_down(lmax, o, 64));
  }
  if (lane == 0){ smin[wv] = lmin; smax[wv] = lmax; }
  __syncthreads();
  if (t == 0){
    float m = smin[0], M = smax[0];
    #pragma unroll
    for (int i = 1; i < 4; i++){ m = fminf(m, smin[i]); M = fmaxf(M, smax[i]); }
    sp[0] = m;
    sp[1] = 1.0f / (M - m);
  }
  __syncthreads();
  float mn = sp[0], inv = sp[1];
  float2 tp = partials[tile];
  float tw = (tp.y - tp.x) * (1.0f / (float)FBINS);
  // thread t owns fine bins [8t, 8t+8): one coalesced uint4 (16 B/lane),
  // monotone fine->coarse map => run-accumulate, ~1-2 atomics/thread
  const uint4* fhp4 = (const uint4*)(finehg + (size_t)tile * (FBINS / 2));
  uint4 pk = fhp4[t];
  unsigned c[8];
  c[0] = pk.x & 0xFFFFu; c[1] = pk.x >> 16;
  c[2] = pk.y & 0xFFFFu; c[3] = pk.y >> 16;
  c[4] = pk.z & 0xFFFFu; c[5] = pk.z >> 16;
  c[6] = pk.w & 0xFFFFu; c[7] = pk.w >> 16;
  int f0 = t << 3;
  unsigned acc = 0;
  int cur = -1;
  #pragma unroll
  for (int i = 0; i < 8; i++){
    if (!c[i]) continue;               // skip-zero keeps run merging valid
    float ctr = tp.x + ((float)(f0 + i) + 0.5f) * tw;
    int cb = min(max((int)(((ctr - mn) * inv) * 256.0f), 0), 255);
    if (cb != cur){
      if (acc) atomicAdd(&ch[cur], acc);
      acc = 0u;
      cur = cb;
    }
    acc += c[i];
  }
  if (acc) atomicAdd(&ch[cur], acc);
  __syncthreads();
  unsigned h = ch[t];
  if (h > MAXV) h = MAXV;
  // inclusive wave64 shuffle scan + cross-wave offsets (2 barriers total)
  unsigned s = h;
  #pragma unroll
  for (int o = 1; o < 64; o <<= 1){
    unsigned nb = __shfl_up(s, o, 64);
    if (lane >= o) s += nb;
  }
  if (lane == 63) wsum[wv] = s;
  __syncthreads();
  unsigned off = 0;
  #pragma unroll
  for (int i = 0; i < 3; i++) if (i < wv) off += wsum[i];
  unsigned total = wsum[0] + wsum[1] + wsum[2] + wsum[3];
  float residual = (16384.0f - (float)total) * (1.0f / 256.0f);
  float cum = ((float)(s + off) + (float)(t + 1) * residual) * (255.0f / 16384.0f);
  // LUT values are exact integers 0..255 — u8 is lossless
  lut[(size_t)tile * BINS + t] =
      (unsigned char)(int)floorf(fminf(fmaxf(cum, 0.0f), 255.0f));
  if (tile == 0){
    if (t == 0) *gmm = make_float2(mn, inv);
    if (t < tail) out[N + t] = (float)y[t];
  }
}

// one block = 8-row strip (i0/i1 uniform: band boundaries 64+128k are 8-aligned)
__global__ __launch_bounds__(256) void k_apply(const float* __restrict__ x,
                                               const float2* __restrict__ gmm,
                                               const unsigned char* __restrict__ lutg,
                                               float* __restrict__ out){
  __shared__ unsigned pkl[2048];    // packed (i0,i1,i0@j+1,i1@j+1) u8x4, 8 KB
  int t = threadIdx.x;
  int strip = blockIdx.x;
  int b = strip >> 7;
  int r0 = (strip & 127) << 3;
  float gi = fminf(fmaxf((r0 + 0.5f) * (1.0f / 128.0f) - 0.5f, 0.0f), 7.0f);
  int i0 = (int)gi;
  int i1 = min(i0 + 1, 7);
  const unsigned char* g0 = lutg + ((size_t)b * 8 + i0) * 2048;
  const unsigned char* g1 = lutg + ((size_t)b * 8 + i1) * 2048;
  #pragma unroll
  for (int e = 0; e < 8; e++){
    int e1 = min(e + 1, 7);           // j+1 clamp folded into the pack
    unsigned r00 = g0[e * 256 + t];
    unsigned r10 = g1[e * 256 + t];
    unsigned r01 = g0[e1 * 256 + t];
    unsigned r11 = g1[e1 * 256 + t];
    pkl[e * 256 + t] = r00 | (r10 << 8) | (r01 << 16) | (r11 << 24);
  }
  float2 mmv = *gmm;
  float mn = mmv.x, inv = mmv.y;
  int j0[4];
  float wx[4];
  #pragma unroll
  for (int c = 0; c < 4; c++){
    int col = (t << 2) + c;
    float gj = fminf(fmaxf((col + 0.5f) * (1.0f / 128.0f) - 0.5f, 0.0f), 7.0f);
    j0[c] = (int)gj;
    wx[c] = gj - (float)j0[c];
  }
  size_t base4 = ((size_t)b * 1024 + r0) * 256;   // float4 units
  __syncthreads();
  #pragma unroll
  for (int r = 0; r < 8; r++){
    int h = r0 + r;
    float giw = fminf(fmaxf((h + 0.5f) * (1.0f / 128.0f) - 0.5f, 0.0f), 7.0f);
    float wy = giw - (float)i0;
    float4 xv = ((const float4*)x)[base4 + r * 256 + t];
    int bi[4];
    bi[0] = min(max((int)(((xv.x - mn) * inv) * 256.0f), 0), 255);
    bi[1] = min(max((int)(((xv.y - mn) * inv) * 256.0f), 0), 255);
    bi[2] = min(max((int)(((xv.z - mn) * inv) * 256.0f), 0), 255);
    bi[3] = min(max((int)(((xv.w - mn) * inv) * 256.0f), 0), 255);
    float res[4];
    #pragma unroll
    for (int c = 0; c < 4; c++){
      unsigned pk = pkl[(j0[c] << 8) + bi[c]];  // ONE b32, bank = bi%32
      float f00 = (float)(pk & 255u);
      float f10 = (float)((pk >> 8) & 255u);
      float f01 = (float)((pk >> 16) & 255u);
      float f11 = (float)(pk >> 24);
      float top = f00 + wx[c] * (f01 - f00);
      float bot = f10 + wx[c] * (f11 - f10);
      res[c] = (top + wy * (bot - top)) * (1.0f / 255.0f);
    }
    ((float4*)out)[base4 + r * 256 + t] = make_float4(res[0], res[1], res[2], res[3]);
  }
}

extern "C" void kernel_launch(void* const* d_in, const int* in_sizes, int n_in,
                              void* d_out, int out_size, void* d_ws, size_t ws_size,
                              hipStream_t stream){
  const float* x = (const float*)d_in[0];
  const int* y = (const int*)d_in[1];
  float* out = (float*)d_out;
  int N = in_sizes[0];
  int B = N >> 20;
  int T = B * 64;
  float2* partials = (float2*)d_ws;
  float2* gmm = (float2*)((char*)d_ws + 8192);
  unsigned* fineh = (unsigned*)((char*)d_ws + 16384);
  unsigned char* lut = (unsigned char*)((char*)d_ws + 16384 + (size_t)T * (FBINS * 2));
  int tail = out_size - N;

  hipLaunchKernelGGL(k_tilestat, dim3(T), dim3(256), 0, stream, x, partials, fineh);
  hipLaunchKernelGGL(k_lut, dim3(T), dim3(256), 0, stream,
                     partials, T, fineh, lut, gmm, y, out, N, tail);
  hipLaunchKernelGGL(k_apply, dim3(B * 128), dim3(256), 0, stream,
                     x, gmm, lut, out);
}